// Round 1
// baseline (681.195 us; speedup 1.0000x reference)
//
#include <hip/hip_runtime.h>
#include <math.h>

// Workspace layout (4-byte units):
//   dinv  : N   float   rsqrt(1+deg)
//   ptr   : N   int     degree histogram -> exclusive CSR starts -> (after fill) inclusive ends
//   bsum  : ceil(N/256) int   block partial sums for the scan
//   csr_r : E   int     source node of each edge, grouped by destination
//   h0    : 16N float   x @ W1
//   t2    : 16N float   relu(gcn1) @ W2
//   g     : 16G float   pooled graph accumulator
// Total ~ 26.5 MB for N=100k, E=3.2M, G=1000.

__global__ void k_init(int* ptr, float* g, int N, int G) {
    int i = blockIdx.x * blockDim.x + threadIdx.x;
    if (i < N)      ptr[i] = 0;
    if (i < G * 16) g[i]   = 0.0f;
}

// degree histogram over destinations (self-loop handled analytically later)
__global__ void k_deg(const int* __restrict__ col, int* __restrict__ ptr, int E) {
    int e = blockIdx.x * blockDim.x + threadIdx.x;
    if (e < E) atomicAdd(&ptr[col[e]], 1);
}

// per-256-block exclusive scan of ptr; emits block totals and dinv = rsqrt(1+deg)
__global__ void k_scan_block(int* __restrict__ ptr, float* __restrict__ dinv,
                             int* __restrict__ bsum, int N) {
    int t = threadIdx.x;
    int i = blockIdx.x * 256 + t;
    int c = (i < N) ? ptr[i] : 0;
    if (i < N) dinv[i] = rsqrtf(1.0f + (float)c);
    __shared__ int s[256];
    s[t] = c;
    __syncthreads();
    for (int off = 1; off < 256; off <<= 1) {
        int x = (t >= off) ? s[t - off] : 0;
        __syncthreads();
        s[t] += x;
        __syncthreads();
    }
    if (i < N) ptr[i] = s[t] - c;               // exclusive within block
    if (t == 255) bsum[blockIdx.x] = s[255];    // block total
}

// single-block scan of the block totals -> exclusive block offsets
__global__ void k_scan_sums(int* __restrict__ bsum, int B) {
    __shared__ int s[256];
    __shared__ int carry;
    int t = threadIdx.x;
    if (t == 0) carry = 0;
    __syncthreads();
    for (int base = 0; base < B; base += 256) {
        int i = base + t;
        int v = (i < B) ? bsum[i] : 0;
        s[t] = v;
        __syncthreads();
        for (int off = 1; off < 256; off <<= 1) {
            int x = (t >= off) ? s[t - off] : 0;
            __syncthreads();
            s[t] += x;
            __syncthreads();
        }
        if (i < B) bsum[i] = s[t] - v + carry;  // exclusive global offset
        __syncthreads();
        if (t == 0) carry += s[255];
        __syncthreads();
    }
}

__global__ void k_scan_add(int* __restrict__ ptr, const int* __restrict__ bsum, int N) {
    int i = blockIdx.x * blockDim.x + threadIdx.x;
    if (i < N) ptr[i] += bsum[i >> 8];
}

// fill CSR: csr_r grouped by destination; ptr[v] becomes inclusive end of v's range
__global__ void k_csr(const int* __restrict__ row, const int* __restrict__ col,
                      int* __restrict__ ptr, int* __restrict__ csr_r, int E) {
    int e = blockIdx.x * blockDim.x + threadIdx.x;
    if (e < E) {
        int pos = atomicAdd(&ptr[col[e]], 1);
        csr_r[pos] = row[e];
    }
}

// h0[v][k] = sum_c x[v][c] * W1[c][k]   (W1 is 3x16 row-major)
__global__ void k_xw1(const float* __restrict__ x, const float* __restrict__ W1,
                      float* __restrict__ h0, int N) {
    int t = blockIdx.x * blockDim.x + threadIdx.x;
    if (t >= N * 16) return;
    int v = t >> 4, k = t & 15;
    float x0 = x[v * 3 + 0], x1 = x[v * 3 + 1], x2 = x[v * 3 + 2];
    h0[t] = x0 * W1[k] + x1 * W1[16 + k] + x2 * W1[32 + k];
}

// layer 1 gather + bias + relu + (h1 @ W2) fused via intra-node shuffle.
// 16 lanes per node; lane k owns feature k. h1 never touches memory.
__global__ void k_gather1(const int* __restrict__ ptr, const int* __restrict__ csr_r,
                          const float* __restrict__ dinv, const float* __restrict__ h0,
                          const float* __restrict__ W2, const float* __restrict__ b1,
                          float* __restrict__ t2, int N) {
    __shared__ float sW[256];
    sW[threadIdx.x] = W2[threadIdx.x];
    __syncthreads();
    int t = blockIdx.x * blockDim.x + threadIdx.x;
    int v = t >> 4, k = t & 15;
    if (v < N) {
        int s = (v == 0) ? 0 : ptr[v - 1];
        int e = ptr[v];
        float acc = 0.0f;
        int i = s;
        for (; i + 1 < e; i += 2) {
            int r0 = csr_r[i], r1 = csr_r[i + 1];
            float w0 = dinv[r0], w1 = dinv[r1];
            acc += w0 * h0[r0 * 16 + k] + w1 * h0[r1 * 16 + k];
        }
        if (i < e) { int r = csr_r[i]; acc += dinv[r] * h0[r * 16 + k]; }
        float d = dinv[v];
        float h = fmaxf(d * (acc + d * h0[v * 16 + k]) + b1[k], 0.0f);
        float o = 0.0f;
#pragma unroll
        for (int j = 0; j < 16; ++j) o += __shfl(h, j, 16) * sW[j * 16 + k];
        t2[v * 16 + k] = o;
    }
}

// layer 2 gather + bias + global_add_pool fused.
__global__ void k_gather2(const int* __restrict__ ptr, const int* __restrict__ csr_r,
                          const float* __restrict__ dinv, const float* __restrict__ t2,
                          const float* __restrict__ b2, const int* __restrict__ batch,
                          float* __restrict__ g, int N) {
    int t = blockIdx.x * blockDim.x + threadIdx.x;
    int v = t >> 4, k = t & 15;
    if (v < N) {
        int s = (v == 0) ? 0 : ptr[v - 1];
        int e = ptr[v];
        float acc = 0.0f;
        int i = s;
        for (; i + 1 < e; i += 2) {
            int r0 = csr_r[i], r1 = csr_r[i + 1];
            float w0 = dinv[r0], w1 = dinv[r1];
            acc += w0 * t2[r0 * 16 + k] + w1 * t2[r1 * 16 + k];
        }
        if (i < e) { int r = csr_r[i]; acc += dinv[r] * t2[r * 16 + k]; }
        float d = dinv[v];
        float val = d * (acc + d * t2[v * 16 + k]) + b2[k];
        atomicAdd(&g[batch[v] * 16 + k], val);
    }
}

// logits = g @ Wl + bl (16x7), then log_softmax over 7. One thread per graph.
__global__ void k_head(const float* __restrict__ g, const float* __restrict__ Wl,
                       const float* __restrict__ bl, float* __restrict__ out, int G) {
    int gi = blockIdx.x * blockDim.x + threadIdx.x;
    if (gi >= G) return;
    float gv[16];
#pragma unroll
    for (int k = 0; k < 16; ++k) gv[k] = g[gi * 16 + k];
    float lo[7];
    float mx = -1e30f;
#pragma unroll
    for (int j = 0; j < 7; ++j) {
        float a = bl[j];
#pragma unroll
        for (int k = 0; k < 16; ++k) a += gv[k] * Wl[k * 7 + j];
        lo[j] = a;
        mx = fmaxf(mx, a);
    }
    float s = 0.0f;
#pragma unroll
    for (int j = 0; j < 7; ++j) s += expf(lo[j] - mx);
    float lse = mx + logf(s);
#pragma unroll
    for (int j = 0; j < 7; ++j) out[gi * 7 + j] = lo[j] - lse;
}

extern "C" void kernel_launch(void* const* d_in, const int* in_sizes, int n_in,
                              void* d_out, int out_size, void* d_ws, size_t ws_size,
                              hipStream_t stream) {
    const float* x    = (const float*)d_in[0];
    const int*   ei   = (const int*)d_in[1];   // [2, E]: row = ei[0:E), col = ei[E:2E)
    // d_in[2] = edge_attr, unused by the reference
    const int*   batch = (const int*)d_in[3];
    const float* W1 = (const float*)d_in[4];
    const float* b1 = (const float*)d_in[5];
    const float* W2 = (const float*)d_in[6];
    const float* b2 = (const float*)d_in[7];
    const float* Wl = (const float*)d_in[8];
    const float* bl = (const float*)d_in[9];
    float* out = (float*)d_out;

    const int N = in_sizes[0] / 3;
    const int E = in_sizes[1] / 2;
    const int G = out_size / 7;

    const int* row = ei;
    const int* col = ei + E;

    const int nB = (N + 255) / 256;   // scan blocks

    char* w = (char*)d_ws;
    float* dinv  = (float*)w;                 w += sizeof(float) * N;
    int*   ptr   = (int*)w;                   w += sizeof(int) * N;
    int*   bsum  = (int*)w;                   w += sizeof(int) * nB;
    int*   csr_r = (int*)w;                   w += sizeof(int) * E;
    float* h0    = (float*)w;                 w += sizeof(float) * 16 * N;
    float* t2    = (float*)w;                 w += sizeof(float) * 16 * N;
    float* g     = (float*)w;                 w += sizeof(float) * 16 * G;

    const int TB = 256;
    const int n16 = N * 16;

    k_init<<<(N + TB - 1) / TB, TB, 0, stream>>>(ptr, g, N, G);
    k_deg<<<(E + TB - 1) / TB, TB, 0, stream>>>(col, ptr, E);
    k_scan_block<<<nB, 256, 0, stream>>>(ptr, dinv, bsum, N);
    k_scan_sums<<<1, 256, 0, stream>>>(bsum, nB);
    k_scan_add<<<(N + TB - 1) / TB, TB, 0, stream>>>(ptr, bsum, N);
    k_csr<<<(E + TB - 1) / TB, TB, 0, stream>>>(row, col, ptr, csr_r, E);
    k_xw1<<<(n16 + TB - 1) / TB, TB, 0, stream>>>(x, W1, h0, N);
    k_gather1<<<(n16 + TB - 1) / TB, TB, 0, stream>>>(ptr, csr_r, dinv, h0, W2, b1, t2, N);
    k_gather2<<<(n16 + TB - 1) / TB, TB, 0, stream>>>(ptr, csr_r, dinv, t2, b2, batch, g, N);
    k_head<<<(G + TB - 1) / TB, TB, 0, stream>>>(g, Wl, bl, out, G);
}

// Round 2
// 342.143 us; speedup vs baseline: 1.9910x; 1.9910x over previous
//
#include <hip/hip_runtime.h>
#include <math.h>

#define CHUNK 8192
#define BSH 9            // bucket shift: 512 nodes per bucket
#define BNODES 512

// Workspace layout (4-byte units):
//   dinv  : N            rsqrt(1+deg)
//   ptrS  : N+1          CSR row starts (ptrS[N] = E)
//   tot   : nb           per-bucket edge totals
//   base  : nb+1         exclusive bucket bases
//   off   : (nb+1)*NBLK  per-(bucket,block) within-chunk exclusive offsets
//   csr   : E            source nodes grouped by destination
//   tempU : max(E,32N)   binned packed edges; later aliased by h0 (16N) + t2 (16N)
//   g     : 16G          pooled graph accumulator

__global__ void k_init(int* tot, float* g, int nb, int G16) {
    int i = blockIdx.x * blockDim.x + threadIdx.x;
    if (i < nb)  tot[i] = 0;
    if (i < G16) g[i]   = 0.0f;
}

// Phase 1: bin this block's 8192-edge chunk by destination bucket.
// Writes a dense permutation of the chunk into temp (no write amplification),
// the per-bucket exclusive offsets into off[b][blk], and bucket totals.
__global__ void k_bin(const int* __restrict__ row, const int* __restrict__ col,
                      int* __restrict__ temp, int* __restrict__ off,
                      int* __restrict__ tot, int E, int NBLK, int nb) {
    __shared__ int cnt[256];
    __shared__ int cur[256];
    __shared__ int sc[256];
    int blk = blockIdx.x;
    int start = blk * CHUNK;
    int cs = E - start; if (cs > CHUNK) cs = CHUNK;
    int t = threadIdx.x;
    cnt[t] = 0;
    __syncthreads();
    for (int i = t; i < cs; i += 256) atomicAdd(&cnt[col[start + i] >> BSH], 1);
    __syncthreads();
    int c = cnt[t];
    sc[t] = c;
    __syncthreads();
    for (int o = 1; o < 256; o <<= 1) {
        int x = (t >= o) ? sc[t - o] : 0;
        __syncthreads();
        sc[t] += x;
        __syncthreads();
    }
    int excl = sc[t] - c;
    if (t < nb) {
        off[t * NBLK + blk] = excl;
        if (c) atomicAdd(&tot[t], c);
    }
    if (t == 0) off[nb * NBLK + blk] = cs;
    cur[t] = excl;
    __syncthreads();
    for (int i = t; i < cs; i += 256) {
        int cc = col[start + i];
        int rr = row[start + i];
        int p = atomicAdd(&cur[cc >> BSH], 1);
        temp[start + p] = (rr << BSH) | (cc & (BNODES - 1));
    }
}

// exclusive scan of bucket totals -> base; also ptrS[N] = E sentinel
__global__ void k_base(const int* __restrict__ tot, int* __restrict__ base,
                       int* __restrict__ ptrS, int E, int nb, int N) {
    __shared__ int s[256];
    int t = threadIdx.x;
    int c = (t < nb) ? tot[t] : 0;
    s[t] = c;
    __syncthreads();
    for (int o = 1; o < 256; o <<= 1) {
        int x = (t >= o) ? s[t - o] : 0;
        __syncthreads();
        s[t] += x;
        __syncthreads();
    }
    if (t < nb) base[t] = s[t] - c;
    if (t == 0) ptrS[N] = E;
}

// Phase 2: one block per bucket. LDS histogram + scan over 512 local nodes,
// write ptrS/dinv coalesced, then scatter csr entries into the bucket's
// L2-hot ~64KB csr window. No global atomics anywhere.
__global__ void k_build(const int* __restrict__ temp, const int* __restrict__ off,
                        const int* __restrict__ base, int* __restrict__ ptrS,
                        float* __restrict__ dinv, int* __restrict__ csr,
                        int NBLK, int N) {
    __shared__ int cnt[BNODES];
    __shared__ int cur[BNODES];
    __shared__ int sc[BNODES];
    int b = blockIdx.x;
    int t = threadIdx.x;   // 512 threads
    cnt[t] = 0;
    __syncthreads();
    for (int seg = t; seg < NBLK; seg += BNODES) {
        int s0 = off[b * NBLK + seg];
        int s1 = off[(b + 1) * NBLK + seg];
        int sb = seg * CHUNK;
        for (int i = s0; i < s1; ++i)
            atomicAdd(&cnt[temp[sb + i] & (BNODES - 1)], 1);
    }
    __syncthreads();
    int c = cnt[t];
    sc[t] = c;
    __syncthreads();
    for (int o = 1; o < BNODES; o <<= 1) {
        int x = (t >= o) ? sc[t - o] : 0;
        __syncthreads();
        sc[t] += x;
        __syncthreads();
    }
    int startp = base[b] + sc[t] - c;
    int node = (b << BSH) + t;
    if (node < N) {
        ptrS[node] = startp;
        dinv[node] = rsqrtf(1.0f + (float)c);
    }
    cur[t] = startp;
    __syncthreads();
    for (int seg = t; seg < NBLK; seg += BNODES) {
        int s0 = off[b * NBLK + seg];
        int s1 = off[(b + 1) * NBLK + seg];
        int sb = seg * CHUNK;
        for (int i = s0; i < s1; ++i) {
            int e = temp[sb + i];
            int p = atomicAdd(&cur[e & (BNODES - 1)], 1);
            csr[p] = e >> BSH;
        }
    }
}

// h0p[v][k] = dinv[v] * sum_c x[v][c] * W1[c][k]   (premultiplied table)
__global__ void k_xw1(const float* __restrict__ x, const float* __restrict__ W1,
                      const float* __restrict__ dinv, float* __restrict__ h0p, int N) {
    int t = blockIdx.x * blockDim.x + threadIdx.x;
    if (t >= N * 16) return;
    int v = t >> 4, k = t & 15;
    float x0 = x[v * 3 + 0], x1 = x[v * 3 + 1], x2 = x[v * 3 + 2];
    h0p[t] = dinv[v] * (x0 * W1[k] + x1 * W1[16 + k] + x2 * W1[32 + k]);
}

// layer 1 gather (pure row-adds on premultiplied table) + relu + W2 via shfl.
// Writes t2p = dinv[v] * (h1 @ W2) so layer 2 is also pure adds.
__global__ void k_gather1(const int* __restrict__ ptrS, const int* __restrict__ csr,
                          const float* __restrict__ dinv, const float* __restrict__ h0p,
                          const float* __restrict__ W2, const float* __restrict__ b1,
                          float* __restrict__ t2p, int N) {
    __shared__ float sW[256];
    sW[threadIdx.x] = W2[threadIdx.x];
    __syncthreads();
    int t = blockIdx.x * blockDim.x + threadIdx.x;
    int v = t >> 4, k = t & 15;
    if (v < N) {
        int s = ptrS[v], e = ptrS[v + 1];
        float a0 = 0.0f, a1 = 0.0f;
        int i = s;
        for (; i + 1 < e; i += 2) {
            a0 += h0p[csr[i] * 16 + k];
            a1 += h0p[csr[i + 1] * 16 + k];
        }
        if (i < e) a0 += h0p[csr[i] * 16 + k];
        float d = dinv[v];
        float h = fmaxf(d * (a0 + a1 + h0p[v * 16 + k]) + b1[k], 0.0f);
        float o = 0.0f;
#pragma unroll
        for (int j = 0; j < 16; ++j) o += __shfl(h, j, 16) * sW[j * 16 + k];
        t2p[v * 16 + k] = d * o;
    }
}

// layer 2 gather + bias + pool with wave-level pre-reduction (batch is sorted,
// so a wave's 4 nodes usually share a graph -> 4x fewer device atomics).
__global__ void k_gather2(const int* __restrict__ ptrS, const int* __restrict__ csr,
                          const float* __restrict__ dinv, const float* __restrict__ t2p,
                          const float* __restrict__ b2, const int* __restrict__ batch,
                          float* __restrict__ g, int N) {
    int t = blockIdx.x * blockDim.x + threadIdx.x;
    int v = t >> 4, k = t & 15;
    bool valid = (v < N);
    float val = 0.0f;
    int bg = 0;
    if (valid) {
        int s = ptrS[v], e = ptrS[v + 1];
        float a0 = 0.0f, a1 = 0.0f;
        int i = s;
        for (; i + 1 < e; i += 2) {
            a0 += t2p[csr[i] * 16 + k];
            a1 += t2p[csr[i + 1] * 16 + k];
        }
        if (i < e) a0 += t2p[csr[i] * 16 + k];
        float d = dinv[v];
        val = d * (a0 + a1 + t2p[v * 16 + k]) + b2[k];
        bg = batch[v];
    }
    int lane = threadIdx.x & 63;
    int bg0 = __shfl(bg, lane & 15, 64);
    bool uni = __all(valid && (bg == bg0));
    if (uni) {
        val += __shfl_xor(val, 16, 64);
        val += __shfl_xor(val, 32, 64);
        if (lane < 16) atomicAdd(&g[bg * 16 + k], val);
    } else if (valid) {
        atomicAdd(&g[bg * 16 + k], val);
    }
}

// logits = g @ Wl + bl (16x7), then log_softmax over 7. One thread per graph.
__global__ void k_head(const float* __restrict__ g, const float* __restrict__ Wl,
                       const float* __restrict__ bl, float* __restrict__ out, int G) {
    int gi = blockIdx.x * blockDim.x + threadIdx.x;
    if (gi >= G) return;
    float gv[16];
#pragma unroll
    for (int k = 0; k < 16; ++k) gv[k] = g[gi * 16 + k];
    float lo[7];
    float mx = -1e30f;
#pragma unroll
    for (int j = 0; j < 7; ++j) {
        float a = bl[j];
#pragma unroll
        for (int k = 0; k < 16; ++k) a += gv[k] * Wl[k * 7 + j];
        lo[j] = a;
        mx = fmaxf(mx, a);
    }
    float s = 0.0f;
#pragma unroll
    for (int j = 0; j < 7; ++j) s += expf(lo[j] - mx);
    float lse = mx + logf(s);
#pragma unroll
    for (int j = 0; j < 7; ++j) out[gi * 7 + j] = lo[j] - lse;
}

extern "C" void kernel_launch(void* const* d_in, const int* in_sizes, int n_in,
                              void* d_out, int out_size, void* d_ws, size_t ws_size,
                              hipStream_t stream) {
    const float* x    = (const float*)d_in[0];
    const int*   ei   = (const int*)d_in[1];   // [2, E]: row = ei[0:E), col = ei[E:2E)
    const int*   batch = (const int*)d_in[3];
    const float* W1 = (const float*)d_in[4];
    const float* b1 = (const float*)d_in[5];
    const float* W2 = (const float*)d_in[6];
    const float* b2 = (const float*)d_in[7];
    const float* Wl = (const float*)d_in[8];
    const float* bl = (const float*)d_in[9];
    float* out = (float*)d_out;

    const int N = in_sizes[0] / 3;
    const int E = in_sizes[1] / 2;
    const int G = out_size / 7;

    const int* row = ei;
    const int* col = ei + E;

    const int NBLK = (E + CHUNK - 1) / CHUNK;
    const int nb   = (N + BNODES - 1) >> BSH;

    int* w = (int*)d_ws;
    float* dinv = (float*)w;            w += N;
    int*   ptrS = w;                    w += N + 1;
    int*   tot  = w;                    w += nb;
    int*   base = w;                    w += nb + 1;
    int*   off  = w;                    w += (nb + 1) * NBLK;
    int*   csr  = w;                    w += E;
    int tempsz = E > 32 * N ? E : 32 * N;
    int*   temp = w;                    w += tempsz;
    float* h0p  = (float*)temp;         // aliases temp (dead after k_build)
    float* t2p  = h0p + 16 * N;
    float* g    = (float*)w;            w += 16 * G;

    const int TB = 256;
    const int n16 = N * 16;
    const int G16 = G * 16;
    const int initn = (G16 > nb) ? G16 : nb;

    k_init<<<(initn + TB - 1) / TB, TB, 0, stream>>>(tot, g, nb, G16);
    k_bin<<<NBLK, 256, 0, stream>>>(row, col, temp, off, tot, E, NBLK, nb);
    k_base<<<1, 256, 0, stream>>>(tot, base, ptrS, E, nb, N);
    k_build<<<nb, BNODES, 0, stream>>>(temp, off, base, ptrS, dinv, csr, NBLK, N);
    k_xw1<<<(n16 + TB - 1) / TB, TB, 0, stream>>>(x, W1, dinv, h0p, N);
    k_gather1<<<(n16 + TB - 1) / TB, TB, 0, stream>>>(ptrS, csr, dinv, h0p, W2, b1, t2p, N);
    k_gather2<<<(n16 + TB - 1) / TB, TB, 0, stream>>>(ptrS, csr, dinv, t2p, b2, batch, g, N);
    k_head<<<(G + TB - 1) / TB, TB, 0, stream>>>(g, Wl, bl, out, G);
}

// Round 3
// 278.392 us; speedup vs baseline: 2.4469x; 1.2290x over previous
//
#include <hip/hip_runtime.h>
#include <math.h>

#define CHUNK 8192
#define BSH 8            // bucket shift: 256 nodes per bucket
#define BNODES 256
#define CAP 12288        // LDS stage capacity per bucket (avg 8184, sigma ~90)

// Workspace layout (4-byte units):
//   dinv  : N            rsqrt(1+deg)
//   ptrS  : N+1          CSR row starts (ptrS[N] = E)
//   tot   : nb           per-bucket edge totals
//   base  : nb+1         exclusive bucket bases (base[nb] = E)
//   off   : (nb+1)*NBLK  ushort per-(bucket,chunk) exclusive offsets (2B each)
//   csr   : E            source nodes grouped by destination
//   tempU : max(E,32N)   binned packed edges; later aliased by h0p (16N) + t2p (16N)
//   g     : 16G          pooled graph accumulator

__global__ void k_init(int* tot, float* g, int nb, int G16) {
    int i = blockIdx.x * blockDim.x + threadIdx.x;
    if (i < nb)  tot[i] = 0;
    if (i < G16) g[i]   = 0.0f;
}

// Phase 1: bin this block's 8192-edge chunk by destination bucket.
// All scattered writes staged in LDS; temp written back as full coalesced lines.
__global__ void k_bin(const int* __restrict__ row, const int* __restrict__ col,
                      int* __restrict__ temp, unsigned short* __restrict__ off,
                      int* __restrict__ tot, int E, int NBLK, int nb) {
    __shared__ int cnt[512];
    __shared__ int cur[512];
    __shared__ int sc[512];
    __shared__ int stage[CHUNK];
    int blk = blockIdx.x;
    int start = blk * CHUNK;
    int cs = E - start; if (cs > CHUNK) cs = CHUNK;
    int t = threadIdx.x;     // 512 threads
    cnt[t] = 0;
    __syncthreads();
    for (int i = t; i < cs; i += 512) atomicAdd(&cnt[col[start + i] >> BSH], 1);
    __syncthreads();
    int c = cnt[t];
    sc[t] = c;
    __syncthreads();
    for (int o = 1; o < 512; o <<= 1) {
        int x = (t >= o) ? sc[t - o] : 0;
        __syncthreads();
        sc[t] += x;
        __syncthreads();
    }
    int excl = sc[t] - c;
    if (t < nb) {
        off[t * NBLK + blk] = (unsigned short)excl;
        if (c) atomicAdd(&tot[t], c);
    }
    if (t == 0) off[nb * NBLK + blk] = (unsigned short)cs;
    cur[t] = excl;
    __syncthreads();
    for (int i = t; i < cs; i += 512) {
        int cc = col[start + i];
        int rr = row[start + i];
        int p = atomicAdd(&cur[cc >> BSH], 1);
        stage[p] = (rr << BSH) | (cc & (BNODES - 1));
    }
    __syncthreads();
    for (int i = t; i < cs; i += 512) temp[start + i] = stage[i];
}

// exclusive scan of bucket totals -> base (carry loop, handles nb>512); sentinels.
__global__ void k_base(const int* __restrict__ tot, int* __restrict__ base,
                       int* __restrict__ ptrS, int E, int nb, int N) {
    __shared__ int s[512];
    __shared__ int carry;
    int t = threadIdx.x;
    if (t == 0) carry = 0;
    __syncthreads();
    for (int b0 = 0; b0 < nb; b0 += 512) {
        int i = b0 + t;
        int v = (i < nb) ? tot[i] : 0;
        s[t] = v;
        __syncthreads();
        for (int o = 1; o < 512; o <<= 1) {
            int x = (t >= o) ? s[t - o] : 0;
            __syncthreads();
            s[t] += x;
            __syncthreads();
        }
        if (i < nb) base[i] = s[t] - v + carry;
        __syncthreads();
        if (t == 0) carry += s[511];
        __syncthreads();
    }
    if (t == 0) { base[nb] = E; ptrS[N] = E; }
}

// Phase 2: one block per 256-node bucket. LDS histogram + scan, then scatter the
// bucket's csr window into an LDS stage and write back fully coalesced.
__global__ void k_build(const int* __restrict__ temp, const unsigned short* __restrict__ off,
                        const int* __restrict__ base, int* __restrict__ ptrS,
                        float* __restrict__ dinv, int* __restrict__ csr,
                        int NBLK, int N) {
    __shared__ int cnt[BNODES];
    __shared__ int cur[BNODES];
    __shared__ int sc[BNODES];
    __shared__ int stage[CAP];
    int b = blockIdx.x;
    int t = threadIdx.x;     // 512 threads
    if (t < BNODES) cnt[t] = 0;
    __syncthreads();
    for (int seg = t; seg < NBLK; seg += 512) {
        int s0 = off[b * NBLK + seg];
        int s1 = off[(b + 1) * NBLK + seg];
        int sb = seg * CHUNK;
        for (int i = s0; i < s1; ++i)
            atomicAdd(&cnt[temp[sb + i] & (BNODES - 1)], 1);
    }
    __syncthreads();
    if (t < BNODES) sc[t] = cnt[t];
    __syncthreads();
    for (int o = 1; o < BNODES; o <<= 1) {
        int x = 0;
        if (t < BNODES && t >= o) x = sc[t - o];
        __syncthreads();
        if (t < BNODES) sc[t] += x;
        __syncthreads();
    }
    int bb = base[b];
    if (t < BNODES) {
        int c = cnt[t];
        int startp = bb + sc[t] - c;
        int node = (b << BSH) + t;
        if (node < N) {
            ptrS[node] = startp;
            dinv[node] = rsqrtf(1.0f + (float)c);
        }
        cur[t] = startp;
    }
    __syncthreads();
    for (int seg = t; seg < NBLK; seg += 512) {
        int s0 = off[b * NBLK + seg];
        int s1 = off[(b + 1) * NBLK + seg];
        int sb = seg * CHUNK;
        for (int i = s0; i < s1; ++i) {
            int e = temp[sb + i];
            int p = atomicAdd(&cur[e & (BNODES - 1)], 1);
            int loc = p - bb;
            int r = e >> BSH;
            if (loc < CAP) stage[loc] = r;
            else           csr[p] = r;     // statistically unreachable overflow
        }
    }
    __syncthreads();
    int total = base[b + 1] - bb;
    if (total > CAP) total = CAP;
    for (int i = t; i < total; i += 512) csr[bb + i] = stage[i];
}

// h0p[v][k] = dinv[v] * sum_c x[v][c] * W1[c][k]   (premultiplied table)
__global__ void k_xw1(const float* __restrict__ x, const float* __restrict__ W1,
                      const float* __restrict__ dinv, float* __restrict__ h0p, int N) {
    int t = blockIdx.x * blockDim.x + threadIdx.x;
    if (t >= N * 16) return;
    int v = t >> 4, k = t & 15;
    float x0 = x[v * 3 + 0], x1 = x[v * 3 + 1], x2 = x[v * 3 + 2];
    h0p[t] = dinv[v] * (x0 * W1[k] + x1 * W1[16 + k] + x2 * W1[32 + k]);
}

// layer 1 gather (pure row-adds, 4-way unrolled) + relu + W2 via shfl.
// Writes t2p = dinv[v] * (h1 @ W2) so layer 2 is also pure adds.
__global__ void k_gather1(const int* __restrict__ ptrS, const int* __restrict__ csr,
                          const float* __restrict__ dinv, const float* __restrict__ h0p,
                          const float* __restrict__ W2, const float* __restrict__ b1,
                          float* __restrict__ t2p, int N) {
    __shared__ float sW[256];
    sW[threadIdx.x] = W2[threadIdx.x];
    __syncthreads();
    int t = blockIdx.x * blockDim.x + threadIdx.x;
    int v = t >> 4, k = t & 15;
    if (v < N) {
        int s = ptrS[v], e = ptrS[v + 1];
        float a0 = 0.0f, a1 = 0.0f, a2 = 0.0f, a3 = 0.0f;
        int i = s;
        for (; i + 3 < e; i += 4) {
            int r0 = csr[i], r1 = csr[i + 1], r2 = csr[i + 2], r3 = csr[i + 3];
            a0 += h0p[r0 * 16 + k];
            a1 += h0p[r1 * 16 + k];
            a2 += h0p[r2 * 16 + k];
            a3 += h0p[r3 * 16 + k];
        }
        for (; i < e; ++i) a0 += h0p[csr[i] * 16 + k];
        float d = dinv[v];
        float h = fmaxf(d * ((a0 + a1) + (a2 + a3) + h0p[v * 16 + k]) + b1[k], 0.0f);
        float o = 0.0f;
#pragma unroll
        for (int j = 0; j < 16; ++j) o += __shfl(h, j, 16) * sW[j * 16 + k];
        t2p[v * 16 + k] = d * o;
    }
}

// layer 2 gather + bias + pool with wave-level pre-reduction (batch is sorted,
// so a wave's 4 nodes usually share a graph -> 4x fewer device atomics).
__global__ void k_gather2(const int* __restrict__ ptrS, const int* __restrict__ csr,
                          const float* __restrict__ dinv, const float* __restrict__ t2p,
                          const float* __restrict__ b2, const int* __restrict__ batch,
                          float* __restrict__ g, int N) {
    int t = blockIdx.x * blockDim.x + threadIdx.x;
    int v = t >> 4, k = t & 15;
    bool valid = (v < N);
    float val = 0.0f;
    int bg = 0;
    if (valid) {
        int s = ptrS[v], e = ptrS[v + 1];
        float a0 = 0.0f, a1 = 0.0f, a2 = 0.0f, a3 = 0.0f;
        int i = s;
        for (; i + 3 < e; i += 4) {
            int r0 = csr[i], r1 = csr[i + 1], r2 = csr[i + 2], r3 = csr[i + 3];
            a0 += t2p[r0 * 16 + k];
            a1 += t2p[r1 * 16 + k];
            a2 += t2p[r2 * 16 + k];
            a3 += t2p[r3 * 16 + k];
        }
        for (; i < e; ++i) a0 += t2p[csr[i] * 16 + k];
        float d = dinv[v];
        val = d * ((a0 + a1) + (a2 + a3) + t2p[v * 16 + k]) + b2[k];
        bg = batch[v];
    }
    int lane = threadIdx.x & 63;
    int bg0 = __shfl(bg, lane & 15, 64);
    bool uni = __all(valid && (bg == bg0));
    if (uni) {
        val += __shfl_xor(val, 16, 64);
        val += __shfl_xor(val, 32, 64);
        if (lane < 16) atomicAdd(&g[bg * 16 + k], val);
    } else if (valid) {
        atomicAdd(&g[bg * 16 + k], val);
    }
}

// logits = g @ Wl + bl (16x7), then log_softmax over 7. One thread per graph.
__global__ void k_head(const float* __restrict__ g, const float* __restrict__ Wl,
                       const float* __restrict__ bl, float* __restrict__ out, int G) {
    int gi = blockIdx.x * blockDim.x + threadIdx.x;
    if (gi >= G) return;
    float gv[16];
#pragma unroll
    for (int k = 0; k < 16; ++k) gv[k] = g[gi * 16 + k];
    float lo[7];
    float mx = -1e30f;
#pragma unroll
    for (int j = 0; j < 7; ++j) {
        float a = bl[j];
#pragma unroll
        for (int k = 0; k < 16; ++k) a += gv[k] * Wl[k * 7 + j];
        lo[j] = a;
        mx = fmaxf(mx, a);
    }
    float s = 0.0f;
#pragma unroll
    for (int j = 0; j < 7; ++j) s += expf(lo[j] - mx);
    float lse = mx + logf(s);
#pragma unroll
    for (int j = 0; j < 7; ++j) out[gi * 7 + j] = lo[j] - lse;
}

extern "C" void kernel_launch(void* const* d_in, const int* in_sizes, int n_in,
                              void* d_out, int out_size, void* d_ws, size_t ws_size,
                              hipStream_t stream) {
    const float* x    = (const float*)d_in[0];
    const int*   ei   = (const int*)d_in[1];   // [2, E]: row = ei[0:E), col = ei[E:2E)
    const int*   batch = (const int*)d_in[3];
    const float* W1 = (const float*)d_in[4];
    const float* b1 = (const float*)d_in[5];
    const float* W2 = (const float*)d_in[6];
    const float* b2 = (const float*)d_in[7];
    const float* Wl = (const float*)d_in[8];
    const float* bl = (const float*)d_in[9];
    float* out = (float*)d_out;

    const int N = in_sizes[0] / 3;
    const int E = in_sizes[1] / 2;
    const int G = out_size / 7;

    const int* row = ei;
    const int* col = ei + E;

    const int NBLK = (E + CHUNK - 1) / CHUNK;
    const int nb   = (N + BNODES - 1) >> BSH;

    int* w = (int*)d_ws;
    float* dinv = (float*)w;            w += N;
    int*   ptrS = w;                    w += N + 1;
    int*   tot  = w;                    w += nb;
    int*   base = w;                    w += nb + 1;
    unsigned short* off = (unsigned short*)w;
    w += ((nb + 1) * NBLK + 1) / 2;     // ushort table, rounded up to int units
    int*   csr  = w;                    w += E;
    int tempsz = E > 32 * N ? E : 32 * N;
    int*   temp = w;                    w += tempsz;
    float* h0p  = (float*)temp;         // aliases temp (dead after k_build)
    float* t2p  = h0p + 16 * N;
    float* g    = (float*)w;            w += 16 * G;

    const int TB = 256;
    const int n16 = N * 16;
    const int G16 = G * 16;
    const int initn = (G16 > nb) ? G16 : nb;

    k_init<<<(initn + TB - 1) / TB, TB, 0, stream>>>(tot, g, nb, G16);
    k_bin<<<NBLK, 512, 0, stream>>>(row, col, temp, off, tot, E, NBLK, nb);
    k_base<<<1, 512, 0, stream>>>(tot, base, ptrS, E, nb, N);
    k_build<<<nb, 512, 0, stream>>>(temp, off, base, ptrS, dinv, csr, NBLK, N);
    k_xw1<<<(n16 + TB - 1) / TB, TB, 0, stream>>>(x, W1, dinv, h0p, N);
    k_gather1<<<(n16 + TB - 1) / TB, TB, 0, stream>>>(ptrS, csr, dinv, h0p, W2, b1, t2p, N);
    k_gather2<<<(n16 + TB - 1) / TB, TB, 0, stream>>>(ptrS, csr, dinv, t2p, b2, batch, g, N);
    k_head<<<(G + TB - 1) / TB, TB, 0, stream>>>(g, Wl, bl, out, G);
}